// Round 14
// baseline (258.365 us; speedup 1.0000x reference)
//
#include <hip/hip_runtime.h>

#define D_FT 128

// ---------------------------------------------------------------------------
// bf16 helpers (round-to-nearest-even; inputs are finite)
// ---------------------------------------------------------------------------
__device__ inline unsigned f2bf(float f) {
    unsigned u = __float_as_uint(f);
    return (u + 0x7FFFu + ((u >> 16) & 1u)) >> 16;
}
__device__ inline unsigned pack2bf(float a, float b) {
    return f2bf(a) | (f2bf(b) << 16);
}
__device__ inline float bf_lo(unsigned u) { return __uint_as_float(u << 16); }
__device__ inline float bf_hi(unsigned u) { return __uint_as_float(u & 0xFFFF0000u); }
__device__ inline float bf_us(unsigned short u) { return __uint_as_float((unsigned)u << 16); }

typedef __attribute__((ext_vector_type(4))) float f32x4;
typedef __attribute__((ext_vector_type(8))) short bf16x8;
union bf8u { bf16x8 v; unsigned u[4]; };

// ---------------------------------------------------------------------------
// PREP kernel (merged): convert X0 -> bf16, convert W -> bf16, build row_ptr.
// All three are independent streaming tasks; one launch instead of three.
// ---------------------------------------------------------------------------
__global__ __launch_bounds__(256) void prep_kernel(
    const float* __restrict__ X0, unsigned* __restrict__ xb, int n4,
    const float* __restrict__ W,  unsigned* __restrict__ wb, int n4w,
    const int* __restrict__ row,  int* __restrict__ ptr, int n_edges, int n_nodes)
{
    const int i = blockIdx.x * 256 + threadIdx.x;
    if (i < n4) {                       // X0 f32 -> bf16 (one float4 -> uint2)
        const float4 x = ((const float4*)X0)[i];
        uint2 v; v.x = pack2bf(x.x, x.y); v.y = pack2bf(x.z, x.w);
        ((uint2*)xb)[i] = v;
    }
    if (i < n4w) {                      // W f32 -> bf16 row-major [o][k]
        const float4 x = ((const float4*)W)[i];
        uint2 v; v.x = pack2bf(x.x, x.y); v.y = pack2bf(x.z, x.w);
        ((uint2*)wb)[i] = v;
    }
    if (i <= n_edges) {                 // row_ptr lower-bound table
        const int lo = (i == 0) ? 0 : row[i - 1] + 1;
        const int hi = (i == n_edges) ? n_nodes : row[i];
        for (int k = lo; k <= hi; ++k) ptr[k] = i;
    }
}

// ---------------------------------------------------------------------------
// FUSED kernel v2: SpMM + alpha-mix + GEMM + beta-mix, one block = 128 nodes.
// v1 lesson (R11): 64KB LDS -> 2 blocks/CU -> 30% occupancy starved the
// gather. Fix: W-bf16 is exactly 32KB = L1-resident; B-fragments load
// straight from global (L1 hits after first touch), LDS holds ONLY the xi
// tile (32KB) -> 4 blocks/CU = 32 waves (HW cap). launch_bounds(512,8)
// pins VGPR <= 64 so registers don't re-cap occupancy.
// Phase 1 (gather) is byte-identical to the R11-validated version.
// ---------------------------------------------------------------------------
__global__ __launch_bounds__(512, 8) void fused_spmm_gemm_kernel(
    const unsigned* __restrict__ X0b,
    const unsigned* __restrict__ Wb,       // bf16 row-major [128][128]
    const int*      __restrict__ col,
    const float*    __restrict__ vals,
    const int*      __restrict__ row_ptr,
    const float*    __restrict__ bias,
    const float*    __restrict__ alpha_p,
    const float*    __restrict__ beta_p,
    float*          __restrict__ out,
    int n_nodes)
{
    __shared__ __align__(16) char ldsXi[32768];   // xi bf16 [128][256B], swizzled

    const int t    = threadIdx.x;
    const int wid  = t >> 6;
    const int lane = t & 63;
    const int bn   = blockIdx.x * 128;
    const float alpha = *alpha_p;

    // ---- phase 1: gather-SpMM, 16 nodes per wave (R11-validated) ----
    for (int i = 0; i < 16; ++i) {
        const int nl   = wid * 16 + i;      // local row 0..127
        const int node = bn + nl;
        unsigned xw = 0;
        if (node < n_nodes) {
            const int ebeg = row_ptr[node];
            const int eend = row_ptr[node + 1];
            float ax = 0.f, ay = 0.f;
            for (int e = ebeg; e < eend; e += 64) {
                const int n = min(64, eend - e);
                int cl = 0; float vl = 0.f;
                if (lane < n) { cl = col[e + lane]; vl = vals[e + lane]; }
                for (int j0 = 0; j0 < n; j0 += 16) {
                    float vv[16]; unsigned xs[16];
                    #pragma unroll
                    for (int j = 0; j < 16; ++j) {
                        const int c = __shfl(cl, j0 + j);   // lanes >= n: c=0
                        vv[j] = __shfl(vl, j0 + j);         // ... v=0
                        xs[j] = X0b[c * 64 + lane];
                    }
                    #pragma unroll
                    for (int j = 0; j < 16; ++j) {
                        ax += vv[j] * bf_lo(xs[j]);
                        ay += vv[j] * bf_hi(xs[j]);
                    }
                }
            }
            const unsigned s = X0b[node * 64 + lane];   // self term (bf16)
            xw = pack2bf((1.f - alpha) * ax + alpha * bf_lo(s),
                         (1.f - alpha) * ay + alpha * bf_hi(s));
        }
        int byte = nl * 256 + lane * 4;
        byte ^= (nl & 7) << 4;
        *(unsigned*)(ldsXi + byte) = xw;
    }
    __syncthreads();

    // ---- phase 2: MFMA; A from LDS xi, B straight from global Wb (L1-hot) --
    const int llo = lane & 15;
    const int lhi = lane >> 4;

    bf16x8 a[4];
    #pragma unroll
    for (int ks = 0; ks < 4; ++ks) {
        const int r = wid * 16 + llo;
        int byte = r * 256 + ks * 64 + lhi * 16;
        byte ^= (r & 7) << 4;
        a[ks] = *(const bf16x8*)(ldsXi + byte);
    }

    f32x4 acc[8];
    #pragma unroll
    for (int n = 0; n < 8; ++n) acc[n] = (f32x4){0.f, 0.f, 0.f, 0.f};

    const char* wbase = (const char*)Wb + llo * 256 + lhi * 16;
    #pragma unroll
    for (int n = 0; n < 8; ++n) {
        const char* wrow = wbase + n * 16 * 256;     // row o = n*16 + llo
        #pragma unroll
        for (int ks = 0; ks < 4; ++ks) {
            const bf16x8 b = *(const bf16x8*)(wrow + ks * 64);
            acc[n] = __builtin_amdgcn_mfma_f32_16x16x32_bf16(a[ks], b, acc[n], 0, 0, 0);
        }
    }

    // ---- epilogue: out = (1-beta)*xi + beta*(acc + bias), pure write ----
    const float beta = *beta_p;
    const float ob = 1.f - beta;
    float bb[8];
    #pragma unroll
    for (int n = 0; n < 8; ++n) bb[n] = bias[n * 16 + llo];

    #pragma unroll
    for (int q = 0; q < 4; ++q) {
        const int rl = wid * 16 + lhi * 4 + q;
        const int R  = bn + rl;
        if (R < n_nodes) {
            #pragma unroll
            for (int n = 0; n < 8; ++n) {
                const int C = n * 16 + llo;
                int byte = rl * 256 + C * 2;
                byte ^= (rl & 7) << 4;
                const float xi = bf_us(*(const unsigned short*)(ldsXi + byte));
                out[(size_t)R * D_FT + C] = ob * xi + beta * (acc[n][q] + bb[n]);
            }
        }
    }
}

// ---------------------------------------------------------------------------
// Fallback kernel 1 (R6-validated): f32 SpMM + alpha mix -> d_out.
// ---------------------------------------------------------------------------
template<bool PTR>
__global__ __launch_bounds__(256) void spmm_mix_kernel(
    const float* __restrict__ X0,
    const int*   __restrict__ row,
    const int*   __restrict__ col,
    const float* __restrict__ vals,
    const int*   __restrict__ row_ptr,
    const float* __restrict__ alpha_p,
    float*       __restrict__ Xi,
    int n_nodes, int n_edges)
{
    const int wave = threadIdx.x >> 6;
    const int lane = threadIdx.x & 63;
    const int node = blockIdx.x * 4 + wave;
    if (node >= n_nodes) return;

    int ebeg, eend;
    if (PTR) {
        ebeg = row_ptr[node];
        eend = row_ptr[node + 1];
    } else {
        int lo0 = 0, hi0 = n_edges, lo1 = 0, hi1 = n_edges;
        while ((lo0 < hi0) || (lo1 < hi1)) {
            int m0 = (lo0 + hi0) >> 1; if (m0 >= n_edges) m0 = n_edges - 1;
            int m1 = (lo1 + hi1) >> 1; if (m1 >= n_edges) m1 = n_edges - 1;
            const int r0v = row[m0];
            const int r1v = row[m1];
            if (lo0 < hi0) { if (r0v < node)     lo0 = m0 + 1; else hi0 = m0; }
            if (lo1 < hi1) { if (r1v < node + 1) lo1 = m1 + 1; else hi1 = m1; }
        }
        ebeg = lo0; eend = lo1;
    }

    const int d0 = lane * 2;
    float ax = 0.f, ay = 0.f;

    for (int e = ebeg; e < eend; e += 64) {
        const int n = min(64, eend - e);
        int cl = 0; float vl = 0.f;
        if (lane < n) { cl = col[e + lane]; vl = vals[e + lane]; }
        for (int j0 = 0; j0 < n; j0 += 16) {
            float2 xs[16]; float vv[16];
            #pragma unroll
            for (int j = 0; j < 16; ++j) {
                const int c = __shfl(cl, j0 + j);
                vv[j] = __shfl(vl, j0 + j);
                xs[j] = *(const float2*)(X0 + (size_t)c * D_FT + d0);
            }
            #pragma unroll
            for (int j = 0; j < 16; ++j) {
                ax += vv[j] * xs[j].x;
                ay += vv[j] * xs[j].y;
            }
        }
    }

    const float alpha = *alpha_p;
    const float2 x0self = *(const float2*)(X0 + (size_t)node * D_FT + d0);
    float2 xi;
    xi.x = (1.f - alpha) * ax + alpha * x0self.x;
    xi.y = (1.f - alpha) * ay + alpha * x0self.y;
    *(float2*)(Xi + (size_t)node * D_FT + d0) = xi;
}

// ---------------------------------------------------------------------------
// Fallback kernel 2 (R6-validated): MFMA gemm-mix, in-place on d_out.
// ---------------------------------------------------------------------------
__global__ __launch_bounds__(256) void gemm_mix_f32_kernel(
    const float* __restrict__ W,
    const float* __restrict__ bias,
    const float* __restrict__ beta_p,
    float*       __restrict__ io,
    int n_nodes)
{
    __shared__ __align__(16) char lds_raw[32768];
    char*  __restrict__ ldsB = lds_raw;
    float* __restrict__ ldsS = (float*)lds_raw;

    const int t   = threadIdx.x;
    const int w   = t >> 6;
    const int l   = t & 63;
    const int lhi = l >> 4;
    const int llo = l & 15;
    const int r0  = blockIdx.x * 64;

    int arow = r0 + w * 16 + llo;
    if (arow >= n_nodes) arow = n_nodes - 1;
    const float* aptr = io + (size_t)arow * D_FT;
    float4 af0[4], af1[4];
    #pragma unroll
    for (int ks = 0; ks < 4; ++ks) {
        const int k0 = ks * 32 + lhi * 8;
        af0[ks] = *(const float4*)(aptr + k0);
        af1[ks] = *(const float4*)(aptr + k0 + 4);
    }

    #pragma unroll
    for (int i = 0; i < 16; ++i) {
        const int f4 = i * 256 + t;
        const int o  = f4 >> 5;
        const int c4 = f4 & 31;
        const float4 x = *(const float4*)(W + (size_t)o * D_FT + c4 * 4);
        uint2 v; v.x = pack2bf(x.x, x.y); v.y = pack2bf(x.z, x.w);
        int byte = o * 256 + c4 * 8;
        byte ^= (o & 7) << 4;
        *(uint2*)(ldsB + byte) = v;
    }
    __syncthreads();

    f32x4 acc[8];
    #pragma unroll
    for (int n = 0; n < 8; ++n) acc[n] = (f32x4){0.f, 0.f, 0.f, 0.f};

    #pragma unroll
    for (int ks = 0; ks < 4; ++ks) {
        bf8u a;
        a.u[0] = pack2bf(af0[ks].x, af0[ks].y);
        a.u[1] = pack2bf(af0[ks].z, af0[ks].w);
        a.u[2] = pack2bf(af1[ks].x, af1[ks].y);
        a.u[3] = pack2bf(af1[ks].z, af1[ks].w);
        const int kb = ks * 64 + lhi * 16;
        #pragma unroll
        for (int n = 0; n < 8; ++n) {
            const int o = n * 16 + llo;
            int byte = o * 256 + kb;
            byte ^= (o & 7) << 4;
            const bf16x8 b = *(const bf16x8*)(ldsB + byte);
            acc[n] = __builtin_amdgcn_mfma_f32_16x16x32_bf16(a.v, b, acc[n], 0, 0, 0);
        }
    }

    __syncthreads();
    #pragma unroll
    for (int n = 0; n < 8; ++n) {
        const int C = n * 16 + llo;
        const int rt = w * 16 + lhi * 4;
        #pragma unroll
        for (int q = 0; q < 4; ++q)
            ldsS[(rt + q) * 128 + C] = acc[n][q];
    }
    __syncthreads();

    const float beta = *beta_p;
    const float ob = 1.f - beta;
    const int c4 = t & 31;
    const int rb = t >> 5;
    const float4 bb = *(const float4*)(bias + c4 * 4);

    #pragma unroll
    for (int i = 0; i < 8; ++i) {
        const int r  = rb * 8 + i;
        const int gr = r0 + r;
        if (gr < n_nodes) {
            const float4 a4  = *(const float4*)(ldsS + r * 128 + c4 * 4);
            const float4 xi4 = *(const float4*)(io + (size_t)gr * D_FT + c4 * 4);
            float4 o;
            o.x = ob * xi4.x + beta * (a4.x + bb.x);
            o.y = ob * xi4.y + beta * (a4.y + bb.y);
            o.z = ob * xi4.z + beta * (a4.z + bb.z);
            o.w = ob * xi4.w + beta * (a4.w + bb.w);
            *(float4*)(io + (size_t)gr * D_FT + c4 * 4) = o;
        }
    }
}

// Fallback row_ptr builder (when not using the merged prep path)
__global__ __launch_bounds__(256) void build_row_ptr_kernel(
    const int* __restrict__ row, int* __restrict__ ptr, int n_edges, int n_nodes)
{
    const int e = blockIdx.x * 256 + threadIdx.x;
    if (e > n_edges) return;
    const int lo = (e == 0) ? 0 : row[e - 1] + 1;
    const int hi = (e == n_edges) ? n_nodes : row[e];
    for (int i = lo; i <= hi; ++i) ptr[i] = e;
}

extern "C" void kernel_launch(void* const* d_in, const int* in_sizes, int n_in,
                              void* d_out, int out_size, void* d_ws, size_t ws_size,
                              hipStream_t stream) {
    // inputs: 0:X (unused) 1:X0 2:row 3:col 4:vals 5:W 6:b 7:alpha 8:beta
    const float* X0    = (const float*)d_in[1];
    const int*   row   = (const int*)  d_in[2];
    const int*   col   = (const int*)  d_in[3];
    const float* vals  = (const float*)d_in[4];
    const float* W     = (const float*)d_in[5];
    const float* b     = (const float*)d_in[6];
    const float* alpha = (const float*)d_in[7];
    const float* beta  = (const float*)d_in[8];
    float* out = (float*)d_out;

    const int n_nodes = in_sizes[1] / D_FT;
    const int n_edges = in_sizes[2];

    const size_t ptr_bytes = (size_t)(n_nodes + 1) * sizeof(int);
    const size_t BFOFF = 524288;                    // row_ptr region, padded
    const size_t BFSZ  = (size_t)n_nodes * 256;     // bf16 X0 [N][128]
    const size_t WBSZ  = (size_t)D_FT * D_FT * 2;   // bf16 W, 32KB
    const bool ptr_ok = (ws_size >= ptr_bytes);
    const bool fused  = ptr_ok && (ws_size >= BFOFF + BFSZ + WBSZ)
                               && (BFOFF >= ptr_bytes);

    if (fused) {
        int*      row_ptr = (int*)d_ws;
        unsigned* X0b     = (unsigned*)((char*)d_ws + BFOFF);
        unsigned* Wbf     = (unsigned*)((char*)d_ws + BFOFF + BFSZ);
        const int n4  = n_nodes * D_FT / 4;
        const int n4w = D_FT * D_FT / 4;
        int span = n4;                       // covers X0 convert
        if (n_edges + 1 > span) span = n_edges + 1;
        if (n4w > span) span = n4w;
        prep_kernel<<<(span + 255) / 256, 256, 0, stream>>>(
            X0, X0b, n4, W, Wbf, n4w, row, row_ptr, n_edges, n_nodes);
        fused_spmm_gemm_kernel<<<(n_nodes + 127) / 128, 512, 0, stream>>>(
            X0b, Wbf, col, vals, row_ptr, b, alpha, beta, out, n_nodes);
    } else if (ptr_ok) {
        int* row_ptr = (int*)d_ws;
        build_row_ptr_kernel<<<(n_edges + 256) / 256, 256, 0, stream>>>(
            row, row_ptr, n_edges, n_nodes);
        spmm_mix_kernel<true><<<(n_nodes + 3) / 4, 256, 0, stream>>>(
            X0, row, col, vals, row_ptr, alpha, out, n_nodes, n_edges);
        gemm_mix_f32_kernel<<<(n_nodes + 63) / 64, 256, 0, stream>>>(
            W, b, beta, out, n_nodes);
    } else {
        spmm_mix_kernel<false><<<(n_nodes + 3) / 4, 256, 0, stream>>>(
            X0, row, col, vals, nullptr, alpha, out, n_nodes, n_edges);
        gemm_mix_f32_kernel<<<(n_nodes + 63) / 64, 256, 0, stream>>>(
            W, b, beta, out, n_nodes);
    }
}

// Round 15
// 238.255 us; speedup vs baseline: 1.0844x; 1.0844x over previous
//
#include <hip/hip_runtime.h>

#define D_FT 128

// ---------------------------------------------------------------------------
// bf16 helpers (round-to-nearest-even; inputs are finite)
// ---------------------------------------------------------------------------
__device__ inline unsigned f2bf(float f) {
    unsigned u = __float_as_uint(f);
    return (u + 0x7FFFu + ((u >> 16) & 1u)) >> 16;
}
__device__ inline unsigned pack2bf(float a, float b) {
    return f2bf(a) | (f2bf(b) << 16);
}
__device__ inline float bf_lo(unsigned u) { return __uint_as_float(u << 16); }
__device__ inline float bf_hi(unsigned u) { return __uint_as_float(u & 0xFFFF0000u); }

typedef __attribute__((ext_vector_type(4))) float f32x4;
typedef __attribute__((ext_vector_type(8))) short bf16x8;
union bf8u { bf16x8 v; unsigned u[4]; };

// ---------------------------------------------------------------------------
// PREP kernel (merged): convert X0 -> bf16 AND build row_ptr. One launch
// instead of two; both are independent streaming tasks.
// ---------------------------------------------------------------------------
__global__ __launch_bounds__(256) void prep_kernel(
    const float* __restrict__ X0, unsigned* __restrict__ xb, int n4,
    const int* __restrict__ row,  int* __restrict__ ptr, int n_edges, int n_nodes)
{
    const int i = blockIdx.x * 256 + threadIdx.x;
    if (i < n4) {                       // X0 f32 -> bf16 (one float4 -> uint2)
        const float4 x = ((const float4*)X0)[i];
        uint2 v; v.x = pack2bf(x.x, x.y); v.y = pack2bf(x.z, x.w);
        ((uint2*)xb)[i] = v;
    }
    if (i <= n_edges) {                 // row_ptr lower-bound table
        const int lo = (i == 0) ? 0 : row[i - 1] + 1;
        const int hi = (i == n_edges) ? n_nodes : row[i];
        for (int k = lo; k <= hi; ++k) ptr[k] = i;
    }
}

// ---------------------------------------------------------------------------
// SpMM + alpha mix (R7-validated GB/XB path, self-term now from bf16 X0b:
// saves the 51MB X0-f32 stream that existed only for the self term).
// One wave per node; lane owns 2 features; edge metadata lane-parallel +
// __shfl broadcast; 16 gathers in flight.
// ---------------------------------------------------------------------------
__global__ __launch_bounds__(256) void spmm_mix_bf16_kernel(
    const unsigned* __restrict__ X0b,
    const int*      __restrict__ col,
    const float*    __restrict__ vals,
    const int*      __restrict__ row_ptr,
    const float*    __restrict__ alpha_p,
    unsigned*       __restrict__ Xi_bf,    // ws: bf16 packed [N][64 words]
    int n_nodes)
{
    const int wave = threadIdx.x >> 6;
    const int lane = threadIdx.x & 63;
    const int node = blockIdx.x * 4 + wave;
    if (node >= n_nodes) return;

    const int ebeg = row_ptr[node];
    const int eend = row_ptr[node + 1];

    float ax = 0.f, ay = 0.f;

    for (int e = ebeg; e < eend; e += 64) {
        const int n = min(64, eend - e);
        int cl = 0; float vl = 0.f;
        if (lane < n) { cl = col[e + lane]; vl = vals[e + lane]; }
        for (int j0 = 0; j0 < n; j0 += 16) {
            float vv[16]; unsigned xs[16];
            #pragma unroll
            for (int j = 0; j < 16; ++j) {
                const int c = __shfl(cl, j0 + j);   // lanes >= n give c=0
                vv[j] = __shfl(vl, j0 + j);         // ... and v=0
                xs[j] = X0b[c * 64 + lane];         // 2 bf16 = 4B/lane
            }
            #pragma unroll
            for (int j = 0; j < 16; ++j) {
                ax += vv[j] * bf_lo(xs[j]);
                ay += vv[j] * bf_hi(xs[j]);
            }
        }
    }

    const float alpha = *alpha_p;
    const unsigned s = X0b[node * 64 + lane];       // self term (bf16, hot)
    Xi_bf[node * 64 + lane] =
        pack2bf((1.f - alpha) * ax + alpha * bf_lo(s),
                (1.f - alpha) * ay + alpha * bf_hi(s));
}

// ---------------------------------------------------------------------------
// GEMM-mix (R7-validated): out = (1-beta)*Xi + beta*(Xi @ W^T + b).
// Xi bf16 in ws feeds MFMA A-fragments directly; W staged bf16 XOR-swizzled
// in 32KB LDS, then LDS reused as f32 [64][128] transpose scratch; float4
// epilogue; out is pure write.
// ---------------------------------------------------------------------------
__global__ __launch_bounds__(256) void gemm_mix_bf16_kernel(
    const float*    __restrict__ W,
    const float*    __restrict__ bias,
    const float*    __restrict__ beta_p,
    const unsigned* __restrict__ xi,      // bf16 packed, 64 words/row
    float*          __restrict__ out,
    int n_nodes)
{
    __shared__ __align__(16) char lds_raw[32768];
    char*  __restrict__ ldsB = lds_raw;             // W [128][128] bf16, swizzled
    float* __restrict__ ldsS = (float*)lds_raw;     // later: out [64][128] f32

    const int t   = threadIdx.x;
    const int w   = t >> 6;
    const int l   = t & 63;
    const int lhi = l >> 4;
    const int llo = l & 15;
    const int r0  = blockIdx.x * 64;

    // ---- A-fragments: direct bf16 loads from ws (issued first) ----
    int arow = r0 + w * 16 + llo;
    if (arow >= n_nodes) arow = n_nodes - 1;
    const char* aptr = (const char*)xi + (size_t)arow * 256;
    bf16x8 a[4];
    #pragma unroll
    for (int ks = 0; ks < 4; ++ks)
        a[ks] = *(const bf16x8*)(aptr + ks * 64 + lhi * 16);

    // ---- stage W (f32 -> bf16, swizzled) ----
    #pragma unroll
    for (int i = 0; i < 16; ++i) {
        const int f4 = i * 256 + t;
        const int o  = f4 >> 5;
        const int c4 = f4 & 31;
        const float4 x = *(const float4*)(W + (size_t)o * D_FT + c4 * 4);
        uint2 v; v.x = pack2bf(x.x, x.y); v.y = pack2bf(x.z, x.w);
        int byte = o * 256 + c4 * 8;
        byte ^= (o & 7) << 4;
        *(uint2*)(ldsB + byte) = v;
    }
    __syncthreads();

    // ---- MFMA: 4 k-slices x 8 col-fragments ----
    f32x4 acc[8];
    #pragma unroll
    for (int n = 0; n < 8; ++n) acc[n] = (f32x4){0.f, 0.f, 0.f, 0.f};

    #pragma unroll
    for (int ks = 0; ks < 4; ++ks) {
        const int kb = ks * 64 + lhi * 16;
        #pragma unroll
        for (int n = 0; n < 8; ++n) {
            const int o = n * 16 + llo;
            int byte = o * 256 + kb;
            byte ^= (o & 7) << 4;
            const bf16x8 b = *(const bf16x8*)(ldsB + byte);
            acc[n] = __builtin_amdgcn_mfma_f32_16x16x32_bf16(a[ks], b, acc[n], 0, 0, 0);
        }
    }

    // ---- transpose acc through LDS (W no longer needed) ----
    __syncthreads();
    #pragma unroll
    for (int n = 0; n < 8; ++n) {
        const int C = n * 16 + llo;
        const int rt = w * 16 + lhi * 4;
        #pragma unroll
        for (int q = 0; q < 4; ++q)
            ldsS[(rt + q) * 128 + C] = acc[n][q];
    }
    __syncthreads();

    // ---- float4 epilogue: residual from bf16 Xi, pure write to out ----
    const float beta = *beta_p;
    const float ob = 1.f - beta;
    const int c4 = t & 31;
    const int rb = t >> 5;
    const float4 bb = *(const float4*)(bias + c4 * 4);

    #pragma unroll
    for (int i = 0; i < 8; ++i) {
        const int r  = rb * 8 + i;
        const int gr = r0 + r;
        if (gr < n_nodes) {
            const float4 a4 = *(const float4*)(ldsS + r * 128 + c4 * 4);
            const uint2  p  = ((const uint2*)(xi + (size_t)gr * 64))[c4];
            float4 o;
            o.x = ob * bf_lo(p.x) + beta * (a4.x + bb.x);
            o.y = ob * bf_hi(p.x) + beta * (a4.y + bb.y);
            o.z = ob * bf_lo(p.y) + beta * (a4.z + bb.z);
            o.w = ob * bf_hi(p.y) + beta * (a4.w + bb.w);
            *(float4*)(out + (size_t)gr * D_FT + c4 * 4) = o;
        }
    }
}

// ---------------------------------------------------------------------------
// Fallback kernel 1 (R6-validated): f32 SpMM + alpha mix -> d_out.
// ---------------------------------------------------------------------------
template<bool PTR>
__global__ __launch_bounds__(256) void spmm_mix_kernel(
    const float* __restrict__ X0,
    const int*   __restrict__ row,
    const int*   __restrict__ col,
    const float* __restrict__ vals,
    const int*   __restrict__ row_ptr,
    const float* __restrict__ alpha_p,
    float*       __restrict__ Xi,
    int n_nodes, int n_edges)
{
    const int wave = threadIdx.x >> 6;
    const int lane = threadIdx.x & 63;
    const int node = blockIdx.x * 4 + wave;
    if (node >= n_nodes) return;

    int ebeg, eend;
    if (PTR) {
        ebeg = row_ptr[node];
        eend = row_ptr[node + 1];
    } else {
        int lo0 = 0, hi0 = n_edges, lo1 = 0, hi1 = n_edges;
        while ((lo0 < hi0) || (lo1 < hi1)) {
            int m0 = (lo0 + hi0) >> 1; if (m0 >= n_edges) m0 = n_edges - 1;
            int m1 = (lo1 + hi1) >> 1; if (m1 >= n_edges) m1 = n_edges - 1;
            const int r0v = row[m0];
            const int r1v = row[m1];
            if (lo0 < hi0) { if (r0v < node)     lo0 = m0 + 1; else hi0 = m0; }
            if (lo1 < hi1) { if (r1v < node + 1) lo1 = m1 + 1; else hi1 = m1; }
        }
        ebeg = lo0; eend = lo1;
    }

    const int d0 = lane * 2;
    float ax = 0.f, ay = 0.f;

    for (int e = ebeg; e < eend; e += 64) {
        const int n = min(64, eend - e);
        int cl = 0; float vl = 0.f;
        if (lane < n) { cl = col[e + lane]; vl = vals[e + lane]; }
        for (int j0 = 0; j0 < n; j0 += 16) {
            float2 xs[16]; float vv[16];
            #pragma unroll
            for (int j = 0; j < 16; ++j) {
                const int c = __shfl(cl, j0 + j);
                vv[j] = __shfl(vl, j0 + j);
                xs[j] = *(const float2*)(X0 + (size_t)c * D_FT + d0);
            }
            #pragma unroll
            for (int j = 0; j < 16; ++j) {
                ax += vv[j] * xs[j].x;
                ay += vv[j] * xs[j].y;
            }
        }
    }

    const float alpha = *alpha_p;
    const float2 x0self = *(const float2*)(X0 + (size_t)node * D_FT + d0);
    float2 xi;
    xi.x = (1.f - alpha) * ax + alpha * x0self.x;
    xi.y = (1.f - alpha) * ay + alpha * x0self.y;
    *(float2*)(Xi + (size_t)node * D_FT + d0) = xi;
}

// ---------------------------------------------------------------------------
// Fallback kernel 2 (R6-validated): MFMA gemm-mix, in-place on d_out.
// ---------------------------------------------------------------------------
__global__ __launch_bounds__(256) void gemm_mix_f32_kernel(
    const float* __restrict__ W,
    const float* __restrict__ bias,
    const float* __restrict__ beta_p,
    float*       __restrict__ io,
    int n_nodes)
{
    __shared__ __align__(16) char lds_raw[32768];
    char*  __restrict__ ldsB = lds_raw;
    float* __restrict__ ldsS = (float*)lds_raw;

    const int t   = threadIdx.x;
    const int w   = t >> 6;
    const int l   = t & 63;
    const int lhi = l >> 4;
    const int llo = l & 15;
    const int r0  = blockIdx.x * 64;

    int arow = r0 + w * 16 + llo;
    if (arow >= n_nodes) arow = n_nodes - 1;
    const float* aptr = io + (size_t)arow * D_FT;
    float4 af0[4], af1[4];
    #pragma unroll
    for (int ks = 0; ks < 4; ++ks) {
        const int k0 = ks * 32 + lhi * 8;
        af0[ks] = *(const float4*)(aptr + k0);
        af1[ks] = *(const float4*)(aptr + k0 + 4);
    }

    #pragma unroll
    for (int i = 0; i < 16; ++i) {
        const int f4 = i * 256 + t;
        const int o  = f4 >> 5;
        const int c4 = f4 & 31;
        const float4 x = *(const float4*)(W + (size_t)o * D_FT + c4 * 4);
        uint2 v; v.x = pack2bf(x.x, x.y); v.y = pack2bf(x.z, x.w);
        int byte = o * 256 + c4 * 8;
        byte ^= (o & 7) << 4;
        *(uint2*)(ldsB + byte) = v;
    }
    __syncthreads();

    f32x4 acc[8];
    #pragma unroll
    for (int n = 0; n < 8; ++n) acc[n] = (f32x4){0.f, 0.f, 0.f, 0.f};

    #pragma unroll
    for (int ks = 0; ks < 4; ++ks) {
        bf8u a;
        a.u[0] = pack2bf(af0[ks].x, af0[ks].y);
        a.u[1] = pack2bf(af0[ks].z, af0[ks].w);
        a.u[2] = pack2bf(af1[ks].x, af1[ks].y);
        a.u[3] = pack2bf(af1[ks].z, af1[ks].w);
        const int kb = ks * 64 + lhi * 16;
        #pragma unroll
        for (int n = 0; n < 8; ++n) {
            const int o = n * 16 + llo;
            int byte = o * 256 + kb;
            byte ^= (o & 7) << 4;
            const bf16x8 b = *(const bf16x8*)(ldsB + byte);
            acc[n] = __builtin_amdgcn_mfma_f32_16x16x32_bf16(a.v, b, acc[n], 0, 0, 0);
        }
    }

    __syncthreads();
    #pragma unroll
    for (int n = 0; n < 8; ++n) {
        const int C = n * 16 + llo;
        const int rt = w * 16 + lhi * 4;
        #pragma unroll
        for (int q = 0; q < 4; ++q)
            ldsS[(rt + q) * 128 + C] = acc[n][q];
    }
    __syncthreads();

    const float beta = *beta_p;
    const float ob = 1.f - beta;
    const int c4 = t & 31;
    const int rb = t >> 5;
    const float4 bb = *(const float4*)(bias + c4 * 4);

    #pragma unroll
    for (int i = 0; i < 8; ++i) {
        const int r  = rb * 8 + i;
        const int gr = r0 + r;
        if (gr < n_nodes) {
            const float4 a4  = *(const float4*)(ldsS + r * 128 + c4 * 4);
            const float4 xi4 = *(const float4*)(io + (size_t)gr * D_FT + c4 * 4);
            float4 o;
            o.x = ob * xi4.x + beta * (a4.x + bb.x);
            o.y = ob * xi4.y + beta * (a4.y + bb.y);
            o.z = ob * xi4.z + beta * (a4.z + bb.z);
            o.w = ob * xi4.w + beta * (a4.w + bb.w);
            *(float4*)(io + (size_t)gr * D_FT + c4 * 4) = o;
        }
    }
}

// Fallback row_ptr builder
__global__ __launch_bounds__(256) void build_row_ptr_kernel(
    const int* __restrict__ row, int* __restrict__ ptr, int n_edges, int n_nodes)
{
    const int e = blockIdx.x * 256 + threadIdx.x;
    if (e > n_edges) return;
    const int lo = (e == 0) ? 0 : row[e - 1] + 1;
    const int hi = (e == n_edges) ? n_nodes : row[e];
    for (int i = lo; i <= hi; ++i) ptr[i] = e;
}

extern "C" void kernel_launch(void* const* d_in, const int* in_sizes, int n_in,
                              void* d_out, int out_size, void* d_ws, size_t ws_size,
                              hipStream_t stream) {
    // inputs: 0:X (unused) 1:X0 2:row 3:col 4:vals 5:W 6:b 7:alpha 8:beta
    const float* X0    = (const float*)d_in[1];
    const int*   row   = (const int*)  d_in[2];
    const int*   col   = (const int*)  d_in[3];
    const float* vals  = (const float*)d_in[4];
    const float* W     = (const float*)d_in[5];
    const float* b     = (const float*)d_in[6];
    const float* alpha = (const float*)d_in[7];
    const float* beta  = (const float*)d_in[8];
    float* out = (float*)d_out;

    const int n_nodes = in_sizes[1] / D_FT;
    const int n_edges = in_sizes[2];

    const size_t ptr_bytes = (size_t)(n_nodes + 1) * sizeof(int);
    const size_t BFOFF = 524288;                    // row_ptr region, padded
    const size_t BFSZ  = (size_t)n_nodes * 256;     // one bf16 [N][128]
    const bool ptr_ok = (ws_size >= ptr_bytes);
    const bool tierA  = ptr_ok && (ws_size >= BFOFF + 2 * BFSZ)
                               && (BFOFF >= ptr_bytes);   // X0b + Xi-bf16

    const int spmm_grid = (n_nodes + 3) / 4;

    if (tierA) {
        int*      row_ptr = (int*)d_ws;
        unsigned* X0b     = (unsigned*)((char*)d_ws + BFOFF);
        unsigned* Xibf    = (unsigned*)((char*)d_ws + BFOFF + BFSZ);
        const int n4 = n_nodes * D_FT / 4;
        int span = n4;
        if (n_edges + 1 > span) span = n_edges + 1;
        prep_kernel<<<(span + 255) / 256, 256, 0, stream>>>(
            X0, X0b, n4, row, row_ptr, n_edges, n_nodes);
        spmm_mix_bf16_kernel<<<spmm_grid, 256, 0, stream>>>(
            X0b, col, vals, row_ptr, alpha, Xibf, n_nodes);
        gemm_mix_bf16_kernel<<<(n_nodes + 63) / 64, 256, 0, stream>>>(
            W, b, beta, Xibf, out, n_nodes);
    } else if (ptr_ok) {
        int* row_ptr = (int*)d_ws;
        build_row_ptr_kernel<<<(n_edges + 256) / 256, 256, 0, stream>>>(
            row, row_ptr, n_edges, n_nodes);
        spmm_mix_kernel<true><<<spmm_grid, 256, 0, stream>>>(
            X0, row, col, vals, row_ptr, alpha, out, n_nodes, n_edges);
        gemm_mix_f32_kernel<<<(n_nodes + 63) / 64, 256, 0, stream>>>(
            W, b, beta, out, n_nodes);
    } else {
        spmm_mix_kernel<false><<<spmm_grid, 256, 0, stream>>>(
            X0, row, col, vals, nullptr, alpha, out, n_nodes, n_edges);
        gemm_mix_f32_kernel<<<(n_nodes + 63) / 64, 256, 0, stream>>>(
            W, b, beta, out, n_nodes);
    }
}